// Round 7
// baseline (206.289 us; speedup 1.0000x reference)
//
#include <hip/hip_runtime.h>
#include <hip/hip_bf16.h>
#include <math.h>

// Problem constants (fixed by the reference)
#define NPTS 50000   // N data points
#define DIM  256     // feature dim (K of the GEMM)
#define BQ   2048    // batch of queries (M of the GEMM)
#define NPAD 50048   // N padded to multiple of 128

#define BK   32
#define CH   32      // n-rows per chunk (iteration granule; no LDS anymore)
#define NCH32 1564   // NPAD/CH
#define NG   64      // n-groups; grid = 8 m-tiles x 64 = 512 = 2 blocks/CU
                     // (register-limited). 64%8==0 -> b%8 = g%8: all 8
                     // m-tiles of a group share one XCD; per-XCD B working
                     // set = 8 groups x 390 KB = 3.1 MB < 4 MB L2.
#define LOG2E 1.4426950408889634f

// ---------- fast-path ws layout (float offsets) ----------
//  acc   [0,      2048)
//  x2h   [2048,   4096)   0.5*log2e*||x||^2
//  t     [4096,  54144)   0.5*log2e*||s||^2 - log2|w|  (+inf when w==0)
//  sgn   [54144, 104192)  label sign
//  xb    [104192, 366336)   bf16 x
//  sb    [366336, 6772480)  bf16 s (NPAD rows, 0-padded)
#define WS_ACC 0
#define WS_X2  2048
#define WS_T   4096
#define WS_SGN 54144
#define WS_XB  104192
#define WS_SB  366336
#define WS_TOTAL_BYTES (6772480ull * 4ull)  // 27,089,920 B

// ---------- v1 fallback ws layout ----------
#define V1_ACC 0
#define V1_X2  2048
#define V1_S2  4096
#define V1_W   54096

typedef __bf16 bf16x8 __attribute__((ext_vector_type(8)));
typedef __bf16 bf16x4 __attribute__((ext_vector_type(4)));
typedef float  f32x4  __attribute__((ext_vector_type(4)));
typedef unsigned int u32;

__device__ __forceinline__ float fast_exp2(float v) {
#if __has_builtin(__builtin_amdgcn_exp2f)
  return __builtin_amdgcn_exp2f(v);   // raw v_exp_f32
#else
  return exp2f(v);
#endif
}

// ============================================================
// FAST PATH (bf16, verified line)
// ============================================================

// One wave per row: fp32->bf16 convert into ws, plus folded epilogue
// constants t = s2h - log2|w| and sign. Blocks 0..7 zero the accumulator.
__global__ __launch_bounds__(256) void svm_precvt9(
    const float* __restrict__ x, const float* __restrict__ s,
    const float* __restrict__ labels, const float* __restrict__ lambdas,
    float* __restrict__ ws) {
  const int wid  = blockIdx.x * 4 + (threadIdx.x >> 6);
  const int lane = threadIdx.x & 63;
  __bf16* xb = (__bf16*)(ws + WS_XB);
  __bf16* sb = (__bf16*)(ws + WS_SB);

  if (blockIdx.x < 8) ws[WS_ACC + blockIdx.x * 256 + threadIdx.x] = 0.0f;

  if (wid < NPAD) {
    float4 v = make_float4(0.f, 0.f, 0.f, 0.f);
    if (wid < NPTS)
      v = reinterpret_cast<const float4*>(s + (size_t)wid * DIM)[lane];
    bf16x4 h = { (__bf16)v.x, (__bf16)v.y, (__bf16)v.z, (__bf16)v.w };
    *reinterpret_cast<bf16x4*>(sb + (size_t)wid * DIM + lane * 4) = h;
    float ss = v.x * v.x + v.y * v.y + v.z * v.z + v.w * v.w;
    #pragma unroll
    for (int off = 32; off > 0; off >>= 1) ss += __shfl_xor(ss, off);
    if (lane == 0) {
      float s2h = 0.5f * LOG2E * ss;
      float lam = (wid < NPTS) ? lambdas[wid] : 0.0f;
      float lab = (wid < NPTS) ? labels[wid] : 1.0f;
      float mag = lam > 0.0f ? lam : 0.0f;
      ws[WS_T + wid]   = (mag > 0.0f) ? s2h - log2f(mag) : __builtin_inff();
      ws[WS_SGN + wid] = lab;
    }
  } else if (wid < NPAD + BQ) {
    int r = wid - NPAD;
    float4 v = reinterpret_cast<const float4*>(x + (size_t)r * DIM)[lane];
    bf16x4 h = { (__bf16)v.x, (__bf16)v.y, (__bf16)v.z, (__bf16)v.w };
    *reinterpret_cast<bf16x4*>(xb + (size_t)r * DIM + lane * 4) = h;
    float ss = v.x * v.x + v.y * v.y + v.z * v.z + v.w * v.w;
    #pragma unroll
    for (int off = 32; off > 0; off >>= 1) ss += __shfl_xor(ss, off);
    if (lane == 0) ws[WS_X2 + r] = 0.5f * LOG2E * ss;
  }
}

// main16: NO LDS. B is L2-resident by construction (3.1 MB/XCD working
// set via the same-XCD group mapping), so LDS staging was pure overhead
// (Common-mistake #7 / m169: dropping staging of L2-fit data = +26%).
// Each wave reads B fragments straight from L2 into VGPRs:
//   bfv[ni] = sb[(c*CH + ni*16 + l16)*256 + kt*32 + quad*8 ..+8)
// (the round-0 write/read swizzle pair cancels; verified algebraically).
// Lanes form 16 x 64 B contiguous segments per load -> well coalesced.
// Zero barriers, zero vmcnt drains: waves drift freely, 2 waves/SIMD
// cross-hide, and the compiler software-pipelines pure-register global
// loads across chunk boundaries (no global_load_lds+barrier pathology).
// mi=4 A-reuse keeps per-wave L2 traffic at 16 KB/chunk; regs ~230 < 256.
__global__ __launch_bounds__(256, 2) void svm_main16(float* __restrict__ ws) {
  const __bf16* xb = (const __bf16*)(ws + WS_XB);
  const __bf16* sb = (const __bf16*)(ws + WS_SB);
  const float* x2g = ws + WS_X2;
  const float* tg  = ws + WS_T;
  const float* sgg = ws + WS_SGN;
  float* accOut    = ws + WS_ACC;

  const int t    = threadIdx.x;
  const int wave = t >> 6;            // 0..3
  const int lane = t & 63;
  const int quad = lane >> 4;
  const int l16  = lane & 15;
  const int g    = blockIdx.x & (NG - 1);  // n-group 0..63 (pow2: exact)
  const int mt   = blockIdx.x >> 6;        // m-tile 0..7 (256 rows each)
  const int m0   = mt * 256;
  const int c0   = (NCH32 * g) / NG;
  const int c1   = (NCH32 * (g + 1)) / NG;

  // A fragments: 4 mi x 8 kt x 16 B = 128 VGPR, loaded once, pinned opaque.
  f32x4 afr[4][8];
  #pragma unroll
  for (int mi = 0; mi < 4; ++mi)
    #pragma unroll
    for (int kt = 0; kt < 8; ++kt)
      afr[mi][kt] = *reinterpret_cast<const f32x4*>(
          xb + (size_t)(m0 + wave * 64 + mi * 16 + l16) * DIM + kt * BK + quad * 8);
  #pragma unroll
  for (int mi = 0; mi < 4; ++mi)
    #pragma unroll
    for (int kt = 0; kt < 8; ++kt)
      asm volatile("" : "+v"(afr[mi][kt]));  // no remat, stays in VGPRs

  float runAcc[4][4] = {{0.f, 0.f, 0.f, 0.f}, {0.f, 0.f, 0.f, 0.f},
                        {0.f, 0.f, 0.f, 0.f}, {0.f, 0.f, 0.f, 0.f}};

  // Per-lane base into this wave's B-fragment stream: row ni*16+l16 of the
  // chunk, col window kt*32 + quad*8.  (quad*8 bf16 = 16 B.)
  const __bf16* bbase = sb + (size_t)l16 * DIM + quad * 8;

  for (int c = c0; c < c1; ++c) {
    // Epilogue constants for this chunk (L2 loads; hide under MFMA).
    float tt[2], sg[2];
    #pragma unroll
    for (int ni = 0; ni < 2; ++ni) {
      int n = c * CH + ni * 16 + l16;
      tt[ni] = tg[n];
      sg[ni] = sgg[n];
    }

    f32x4 acc[4][2];
    #pragma unroll
    for (int mi = 0; mi < 4; ++mi)
      #pragma unroll
      for (int ni = 0; ni < 2; ++ni)
        acc[mi][ni] = (f32x4)(0.0f);

    const __bf16* bchunk = bbase + (size_t)c * CH * DIM;

    #pragma unroll
    for (int kt = 0; kt < 8; ++kt) {
      bf16x8 bfv[2];
      #pragma unroll
      for (int ni = 0; ni < 2; ++ni)
        bfv[ni] = *reinterpret_cast<const bf16x8*>(
            bchunk + (size_t)(ni * 16) * DIM + kt * BK);
      #pragma unroll
      for (int mi = 0; mi < 4; ++mi)
        #pragma unroll
        for (int ni = 0; ni < 2; ++ni)
          acc[mi][ni] = __builtin_amdgcn_mfma_f32_16x16x32_bf16(
              __builtin_bit_cast(bf16x8, afr[mi][kt]), bfv[ni],
              acc[mi][ni], 0, 0, 0);
    }

    // Hoisted epilogue: p += sgn * exp2(dot*log2e - t_n); x2 applied at end.
    #pragma unroll
    for (int mi = 0; mi < 4; ++mi)
      #pragma unroll
      for (int reg = 0; reg < 4; ++reg) {
        float p = runAcc[mi][reg];
        #pragma unroll
        for (int ni = 0; ni < 2; ++ni)
          p = __builtin_fmaf(sg[ni],
                fast_exp2(__builtin_fmaf(acc[mi][ni][reg], LOG2E, -tt[ni])), p);
        runAcc[mi][reg] = p;
      }
  }

  // reduce over the 16 n-column lanes; scale by exp2(-x2h); one atomic/row.
  #pragma unroll
  for (int mi = 0; mi < 4; ++mi)
    #pragma unroll
    for (int reg = 0; reg < 4; ++reg) {
      float v = runAcc[mi][reg];
      v += __shfl_xor(v, 1);
      v += __shfl_xor(v, 2);
      v += __shfl_xor(v, 4);
      v += __shfl_xor(v, 8);
      if (l16 == 0) {
        int row = m0 + wave * 64 + mi * 16 + quad * 4 + reg;
        atomicAdd(&accOut[row], fast_exp2(-x2g[row]) * v);
      }
    }
}

// ============================================================
// V1 FALLBACK (used only if ws_size too small)
// ============================================================

__global__ __launch_bounds__(256) void svm_precompute(
    const float* __restrict__ x, const float* __restrict__ s,
    const float* __restrict__ labels, const float* __restrict__ lambdas,
    float* __restrict__ ws) {
  int wid  = blockIdx.x * 4 + (threadIdx.x >> 6);
  int lane = threadIdx.x & 63;
  const float* src;
  if (wid < NPTS)           src = s + (size_t)wid * DIM;
  else if (wid < NPTS + BQ) src = x + (size_t)(wid - NPTS) * DIM;
  else return;
  float4 v = reinterpret_cast<const float4*>(src)[lane];
  float ss = v.x * v.x + v.y * v.y + v.z * v.z + v.w * v.w;
  #pragma unroll
  for (int off = 32; off > 0; off >>= 1) ss += __shfl_xor(ss, off);
  if (lane == 0) {
    if (wid < NPTS) {
      ws[V1_S2 + wid] = ss;
      float lam = lambdas[wid];
      ws[V1_W + wid] = labels[wid] * (lam > 0.0f ? lam : 0.0f);
    } else {
      ws[V1_X2 + (wid - NPTS)] = ss;
    }
  }
}

__global__ __launch_bounds__(256) void svm_main(
    const float* __restrict__ x, const float* __restrict__ s,
    const float* __restrict__ ws) {
  __shared__ __bf16 sA[128 * BK];
  __shared__ __bf16 sB2[128 * BK];

  const int t    = threadIdx.x;
  const int wave = t >> 6;
  const int lane = t & 63;
  const int quad = lane >> 4;
  const int l16  = lane & 15;
  const int wm   = (wave & 1) * 64;
  const int wn   = (wave >> 1) * 64;
  const int bRow0 = blockIdx.y * 128;
  const int n0    = blockIdx.x * 128;

  f32x4 acc[4][4];
  #pragma unroll
  for (int i = 0; i < 4; ++i)
    #pragma unroll
    for (int j = 0; j < 4; ++j)
      acc[i][j] = (f32x4)(0.0f);

  for (int kt = 0; kt < DIM / BK; ++kt) {
    const int k0 = kt * BK;
    __syncthreads();
    #pragma unroll
    for (int i = 0; i < 4; ++i) {
      int slot = t + i * 256;
      int r  = slot >> 3;
      int c4 = slot & 7;
      float4 va = reinterpret_cast<const float4*>(
          x + (size_t)(bRow0 + r) * DIM + k0)[c4];
      bf16x4 ha = { (__bf16)va.x, (__bf16)va.y, (__bf16)va.z, (__bf16)va.w };
      *reinterpret_cast<bf16x4*>(&sA[r * BK + c4 * 4]) = ha;

      int nrow = n0 + r;
      float4 vb = make_float4(0.f, 0.f, 0.f, 0.f);
      if (nrow < NPTS)
        vb = reinterpret_cast<const float4*>(
            s + (size_t)nrow * DIM + k0)[c4];
      bf16x4 hb = { (__bf16)vb.x, (__bf16)vb.y, (__bf16)vb.z, (__bf16)vb.w };
      *reinterpret_cast<bf16x4*>(&sB2[r * BK + c4 * 4]) = hb;
    }
    __syncthreads();

    bf16x8 af[4], bfv[4];
    #pragma unroll
    for (int mi = 0; mi < 4; ++mi)
      af[mi] = *reinterpret_cast<const bf16x8*>(
          &sA[(wm + mi * 16 + l16) * BK + quad * 8]);
    #pragma unroll
    for (int ni = 0; ni < 4; ++ni)
      bfv[ni] = *reinterpret_cast<const bf16x8*>(
          &sB2[(wn + ni * 16 + l16) * BK + quad * 8]);
    #pragma unroll
    for (int mi = 0; mi < 4; ++mi)
      #pragma unroll
      for (int ni = 0; ni < 4; ++ni)
        acc[mi][ni] = __builtin_amdgcn_mfma_f32_16x16x32_bf16(
            af[mi], bfv[ni], acc[mi][ni], 0, 0, 0);
  }

  const float* x2g = ws + V1_X2;
  const float* s2g = ws + V1_S2;
  const float* wg  = ws + V1_W;
  float* accOut    = (float*)ws + V1_ACC;

  float s2v[4], wv[4];
  #pragma unroll
  for (int ni = 0; ni < 4; ++ni) {
    int n = n0 + wn + ni * 16 + l16;
    bool ok = n < NPTS;
    s2v[ni] = ok ? s2g[n] : 0.0f;
    wv[ni]  = ok ? wg[n]  : 0.0f;
  }
  #pragma unroll
  for (int mi = 0; mi < 4; ++mi) {
    const int mbase = wm + mi * 16 + quad * 4;
    #pragma unroll
    for (int reg = 0; reg < 4; ++reg) {
      float x2r = x2g[bRow0 + mbase + reg];
      float ps = 0.0f;
      #pragma unroll
      for (int ni = 0; ni < 4; ++ni) {
        float cc = acc[mi][ni][reg];
        ps += __expf(__builtin_fmaf(-0.5f, x2r + s2v[ni], cc)) * wv[ni];
      }
      ps += __shfl_xor(ps, 1);
      ps += __shfl_xor(ps, 2);
      ps += __shfl_xor(ps, 4);
      ps += __shfl_xor(ps, 8);
      if (l16 == 0) atomicAdd(&accOut[bRow0 + mbase + reg], ps);
    }
  }
}

// ============================================================

__global__ __launch_bounds__(256) void svm_finalize(
    const float* __restrict__ ws, const float* __restrict__ bias,
    float* __restrict__ out) {
  int i = blockIdx.x * 256 + threadIdx.x;
  if (i < BQ) out[i] = tanhf(ws[i] + bias[0]);  // acc at offset 0 in all layouts
}

extern "C" void kernel_launch(void* const* d_in, const int* in_sizes, int n_in,
                              void* d_out, int out_size, void* d_ws, size_t ws_size,
                              hipStream_t stream) {
  const float* x       = (const float*)d_in[0];  // [2048, 256]
  const float* s       = (const float*)d_in[1];  // [50000, 256]
  const float* labels  = (const float*)d_in[2];  // [50000]
  const float* lambdas = (const float*)d_in[3];  // [50000]
  const float* bias    = (const float*)d_in[4];  // [1]
  float* out = (float*)d_out;                    // [2048]
  float* ws  = (float*)d_ws;

  if (ws_size >= WS_TOTAL_BYTES) {
    // precvt9 zeroes the accumulator region itself (blocks 0..7)
    svm_precvt9<<<(NPAD + BQ + 3) / 4, 256, 0, stream>>>(x, s, labels, lambdas, ws);
    svm_main16<<<8 * NG, 256, 0, stream>>>(ws);
  } else {
    hipMemsetAsync(ws, 0, BQ * sizeof(float), stream);
    svm_precompute<<<(NPTS + BQ + 3) / 4, 256, 0, stream>>>(x, s, labels, lambdas, ws);
    dim3 grid(391, BQ / 128);
    svm_main<<<grid, 256, 0, stream>>>(x, s, ws);
  }
  svm_finalize<<<BQ / 256, 256, 0, stream>>>(ws, bias, out);
}

// Round 8
// 153.028 us; speedup vs baseline: 1.3480x; 1.3480x over previous
//
#include <hip/hip_runtime.h>
#include <hip/hip_bf16.h>
#include <math.h>

// Problem constants (fixed by the reference)
#define NPTS 50000   // N data points
#define DIM  256     // feature dim (K of the GEMM)
#define BQ   2048    // batch of queries (M of the GEMM)
#define NPAD 50048   // N padded to multiple of 128

#define BK   32
#define CH   32      // n-rows per LDS chunk (16 KB per buffer)
#define NCH32 1564   // NPAD/CH
#define NG   64      // n-groups; grid = 8 m-tiles x 64 = 512 = 2 blocks/CU
                     // (register-limited). 64%8==0 -> b%8 = g%8: all 8
                     // m-tiles of a group share one XCD (B L2-resident).
#define LOG2E 1.4426950408889634f

// ---------- fast-path ws layout (float offsets) ----------
//  acc   [0,      2048)
//  x2h   [2048,   4096)   0.5*log2e*||x||^2
//  t     [4096,  54144)   0.5*log2e*||s||^2 - log2|w|  (+inf when w==0)
//  sgn   [54144, 104192)  label sign
//  xb    [104192, 366336)   bf16 x
//  sb    [366336, 6772480)  bf16 s (NPAD rows, 0-padded)
#define WS_ACC 0
#define WS_X2  2048
#define WS_T   4096
#define WS_SGN 54144
#define WS_XB  104192
#define WS_SB  366336
#define WS_TOTAL_BYTES (6772480ull * 4ull)  // 27,089,920 B

// ---------- v1 fallback ws layout ----------
#define V1_ACC 0
#define V1_X2  2048
#define V1_S2  4096
#define V1_W   54096

typedef __bf16 bf16x8 __attribute__((ext_vector_type(8)));
typedef __bf16 bf16x4 __attribute__((ext_vector_type(4)));
typedef float  f32x4  __attribute__((ext_vector_type(4)));
typedef unsigned int u32;

__device__ __forceinline__ float fast_exp2(float v) {
#if __has_builtin(__builtin_amdgcn_exp2f)
  return __builtin_amdgcn_exp2f(v);   // raw v_exp_f32
#else
  return exp2f(v);
#endif
}

__device__ __forceinline__ void async_copy16(const __bf16* g, __bf16* l) {
  __builtin_amdgcn_global_load_lds(
      (const __attribute__((address_space(1))) u32*)g,
      (__attribute__((address_space(3))) u32*)l, 16, 0, 0);
}

// ============================================================
// FAST PATH (bf16, verified line)
// ============================================================

// One wave per row: fp32->bf16 convert into ws, plus folded epilogue
// constants t = s2h - log2|w| and sign. Blocks 0..7 zero the accumulator.
__global__ __launch_bounds__(256) void svm_precvt9(
    const float* __restrict__ x, const float* __restrict__ s,
    const float* __restrict__ labels, const float* __restrict__ lambdas,
    float* __restrict__ ws) {
  const int wid  = blockIdx.x * 4 + (threadIdx.x >> 6);
  const int lane = threadIdx.x & 63;
  __bf16* xb = (__bf16*)(ws + WS_XB);
  __bf16* sb = (__bf16*)(ws + WS_SB);

  if (blockIdx.x < 8) ws[WS_ACC + blockIdx.x * 256 + threadIdx.x] = 0.0f;

  if (wid < NPAD) {
    float4 v = make_float4(0.f, 0.f, 0.f, 0.f);
    if (wid < NPTS)
      v = reinterpret_cast<const float4*>(s + (size_t)wid * DIM)[lane];
    bf16x4 h = { (__bf16)v.x, (__bf16)v.y, (__bf16)v.z, (__bf16)v.w };
    *reinterpret_cast<bf16x4*>(sb + (size_t)wid * DIM + lane * 4) = h;
    float ss = v.x * v.x + v.y * v.y + v.z * v.z + v.w * v.w;
    #pragma unroll
    for (int off = 32; off > 0; off >>= 1) ss += __shfl_xor(ss, off);
    if (lane == 0) {
      float s2h = 0.5f * LOG2E * ss;
      float lam = (wid < NPTS) ? lambdas[wid] : 0.0f;
      float lab = (wid < NPTS) ? labels[wid] : 1.0f;
      float mag = lam > 0.0f ? lam : 0.0f;
      ws[WS_T + wid]   = (mag > 0.0f) ? s2h - log2f(mag) : __builtin_inff();
      ws[WS_SGN + wid] = lab;
    }
  } else if (wid < NPAD + BQ) {
    int r = wid - NPAD;
    float4 v = reinterpret_cast<const float4*>(x + (size_t)r * DIM)[lane];
    bf16x4 h = { (__bf16)v.x, (__bf16)v.y, (__bf16)v.z, (__bf16)v.w };
    *reinterpret_cast<bf16x4*>(xb + (size_t)r * DIM + lane * 4) = h;
    float ss = v.x * v.x + v.y * v.y + v.z * v.z + v.w * v.w;
    #pragma unroll
    for (int off = 32; off > 0; off >>= 1) ss += __shfl_xor(ss, off);
    if (lane == 0) ws[WS_X2 + r] = 0.5f * LOG2E * ss;
  }
}

// main18 = main15's data path (mi=4/ni=2, afr pinned, dbuf 2x16 KB, same
// zero-conflict swizzles) restructured into the m201/T3+T4+T5 phase
// schedule. Pipe ledger said main15 ran ds/MFMA/VALU nearly SERIALIZED
// (sum 129 kcyc ~= measured 148; overlapped floor is 60.7 = 25 us).
// Per chunk: 2 phases {stage-half || ds_read 4kt -> s_barrier ->
// lgkmcnt(0)+sched_barrier -> setprio(1) 32 MFMA setprio(0) -> s_barrier},
// epilogue after phase B (overlaps other block's prio-1 MFMAs = T5
// role-split), chunk-boundary vmcnt(0) covered by a full chunk of compute.
// Raw s_barrier (NOT __syncthreads) keeps stage loads in flight across
// phases; "memory"-clobbered waitcnt asm + sched_barrier(0) per rule #18.
__global__ __launch_bounds__(256, 2) void svm_main18(float* __restrict__ ws) {
  // [buf][kt][n=32][32k] with 16B slot swizzle: slot(n,c) = c ^ ((n>>1)&3)
  __shared__ __bf16 sB[2][8 * CH * 32];  // 2 x 16 KB

  const __bf16* xb = (const __bf16*)(ws + WS_XB);
  const __bf16* sb = (const __bf16*)(ws + WS_SB);
  const float* x2g = ws + WS_X2;
  const float* tg  = ws + WS_T;
  const float* sgg = ws + WS_SGN;
  float* accOut    = ws + WS_ACC;

  const int t    = threadIdx.x;
  const int wave = t >> 6;            // 0..3
  const int lane = t & 63;
  const int quad = lane >> 4;
  const int l16  = lane & 15;
  const int g    = blockIdx.x & (NG - 1);  // n-group 0..63 (pow2: exact)
  const int mt   = blockIdx.x >> 6;        // m-tile 0..7 (256 rows each)
  const int m0   = mt * 256;
  const int c0   = (NCH32 * g) / NG;
  const int c1   = (NCH32 * (g + 1)) / NG;

  // staging source swizzle (lane-only): slot fetched = (l&3) ^ ((l>>3)&3)
  const int srcswz = ((lane & 3) ^ ((lane >> 3) & 3)) * 8;  // bf16 elems
  // read-side swizzled 16B slot for this lane's B fragment
  const int rdswz = (quad ^ ((l16 >> 1) & 3)) * 8;          // bf16 elems

  // half h of chunk cc staging into buf: 2 x 1 KB gll per wave.
#define STAGE_HALF(buf, cc, h)                                                \
  do {                                                                        \
    _Pragma("unroll")                                                         \
    for (int i = (h) * 2; i < (h) * 2 + 2; ++i) {                             \
      int chn = wave * 4 + i;            /* 0..15 */                          \
      int kt = chn >> 1;                 /* 0..7  */                          \
      int nb = (chn & 1) * 16;           /* 0,16  */                          \
      const __bf16* src = sb + (size_t)((cc) * CH + nb + (lane >> 2)) * DIM   \
                             + kt * BK + srcswz;                              \
      async_copy16(src, &sB[(buf)][kt * (CH * 32) + nb * 32] + lane * 8);     \
    }                                                                         \
  } while (0)

  // Prologue: stage chunk c0 into buf 0; fetch flies under the A-loads.
  STAGE_HALF(0, c0, 0);
  STAGE_HALF(0, c0, 1);

  // A fragments: 4 mi x 8 kt x 16 B = 128 VGPR, loaded once, pinned opaque.
  f32x4 afr[4][8];
  #pragma unroll
  for (int mi = 0; mi < 4; ++mi)
    #pragma unroll
    for (int kt = 0; kt < 8; ++kt)
      afr[mi][kt] = *reinterpret_cast<const f32x4*>(
          xb + (size_t)(m0 + wave * 64 + mi * 16 + l16) * DIM + kt * BK + quad * 8);
  #pragma unroll
  for (int mi = 0; mi < 4; ++mi)
    #pragma unroll
    for (int kt = 0; kt < 8; ++kt)
      asm volatile("" : "+v"(afr[mi][kt]));  // no remat, stays in VGPRs

  float runAcc[4][4] = {{0.f, 0.f, 0.f, 0.f}, {0.f, 0.f, 0.f, 0.f},
                        {0.f, 0.f, 0.f, 0.f}, {0.f, 0.f, 0.f, 0.f}};

  asm volatile("s_waitcnt vmcnt(0)" ::: "memory");
  __builtin_amdgcn_s_barrier();  // chunk c0 resident in sB[0]

  int cur = 0;
  for (int c = c0; c < c1; ++c) {
    // tt/sg for THIS chunk, issued first: in-order vmcnt means the
    // epilogue's implicit wait for them leaves the stage loads in flight.
    float tt[2], sg[2];
    #pragma unroll
    for (int ni = 0; ni < 2; ++ni) {
      int n = c * CH + ni * 16 + l16;
      tt[ni] = tg[n];
      sg[ni] = sgg[n];
    }

    const bool pf = (c + 1 < c1);

    f32x4 acc[4][2];
    #pragma unroll
    for (int mi = 0; mi < 4; ++mi)
      #pragma unroll
      for (int ni = 0; ni < 2; ++ni)
        acc[mi][ni] = (f32x4)(0.0f);

    // ---------------- phase A: kt 0..3 ----------------
    if (pf) STAGE_HALF(cur ^ 1, c + 1, 0);
    bf16x8 bA[4][2];
    #pragma unroll
    for (int kt = 0; kt < 4; ++kt)
      #pragma unroll
      for (int ni = 0; ni < 2; ++ni)
        bA[kt][ni] = *reinterpret_cast<const bf16x8*>(
            &sB[cur][kt * (CH * 32) + (ni * 16 + l16) * 32 + rdswz]);
    __builtin_amdgcn_s_barrier();
    asm volatile("s_waitcnt lgkmcnt(0)" ::: "memory");
    __builtin_amdgcn_sched_barrier(0);
    __builtin_amdgcn_s_setprio(1);
    #pragma unroll
    for (int kt = 0; kt < 4; ++kt)
      #pragma unroll
      for (int mi = 0; mi < 4; ++mi)
        #pragma unroll
        for (int ni = 0; ni < 2; ++ni)
          acc[mi][ni] = __builtin_amdgcn_mfma_f32_16x16x32_bf16(
              __builtin_bit_cast(bf16x8, afr[mi][kt]), bA[kt][ni],
              acc[mi][ni], 0, 0, 0);
    __builtin_amdgcn_s_setprio(0);
    __builtin_amdgcn_s_barrier();

    // ---------------- phase B: kt 4..7 ----------------
    if (pf) STAGE_HALF(cur ^ 1, c + 1, 1);
    bf16x8 bB[4][2];
    #pragma unroll
    for (int kt = 0; kt < 4; ++kt)
      #pragma unroll
      for (int ni = 0; ni < 2; ++ni)
        bB[kt][ni] = *reinterpret_cast<const bf16x8*>(
            &sB[cur][(kt + 4) * (CH * 32) + (ni * 16 + l16) * 32 + rdswz]);
    __builtin_amdgcn_s_barrier();
    asm volatile("s_waitcnt lgkmcnt(0)" ::: "memory");
    __builtin_amdgcn_sched_barrier(0);
    __builtin_amdgcn_s_setprio(1);
    #pragma unroll
    for (int kt = 0; kt < 4; ++kt)
      #pragma unroll
      for (int mi = 0; mi < 4; ++mi)
        #pragma unroll
        for (int ni = 0; ni < 2; ++ni)
          acc[mi][ni] = __builtin_amdgcn_mfma_f32_16x16x32_bf16(
              __builtin_bit_cast(bf16x8, afr[mi][kt + 4]), bB[kt][ni],
              acc[mi][ni], 0, 0, 0);
    __builtin_amdgcn_s_setprio(0);
    __builtin_amdgcn_s_barrier();

    // ---------------- epilogue (VALU/trans) ----------------
    // Runs at prio 0: the co-resident block's prio-1 MFMAs win the SIMD
    // while we burn the exp/fma pipe (T5 role-split across blocks).
    #pragma unroll
    for (int mi = 0; mi < 4; ++mi)
      #pragma unroll
      for (int reg = 0; reg < 4; ++reg) {
        float p = runAcc[mi][reg];
        #pragma unroll
        for (int ni = 0; ni < 2; ++ni)
          p = __builtin_fmaf(sg[ni],
                fast_exp2(__builtin_fmaf(acc[mi][ni][reg], LOG2E, -tt[ni])), p);
        runAcc[mi][reg] = p;
      }

    // ---------------- chunk boundary ----------------
    // vmcnt(0): c+1's 4 gll have had the whole chunk to land (covered).
    // Barrier: cross-wave "everyone's staging done / reads done".
    asm volatile("s_waitcnt vmcnt(0)" ::: "memory");
    __builtin_amdgcn_s_barrier();
    cur ^= 1;
  }

  // reduce over the 16 n-column lanes; scale by exp2(-x2h); one atomic/row.
  #pragma unroll
  for (int mi = 0; mi < 4; ++mi)
    #pragma unroll
    for (int reg = 0; reg < 4; ++reg) {
      float v = runAcc[mi][reg];
      v += __shfl_xor(v, 1);
      v += __shfl_xor(v, 2);
      v += __shfl_xor(v, 4);
      v += __shfl_xor(v, 8);
      if (l16 == 0) {
        int row = m0 + wave * 64 + mi * 16 + quad * 4 + reg;
        atomicAdd(&accOut[row], fast_exp2(-x2g[row]) * v);
      }
    }
#undef STAGE_HALF
}

// ============================================================
// V1 FALLBACK (used only if ws_size too small)
// ============================================================

__global__ __launch_bounds__(256) void svm_precompute(
    const float* __restrict__ x, const float* __restrict__ s,
    const float* __restrict__ labels, const float* __restrict__ lambdas,
    float* __restrict__ ws) {
  int wid  = blockIdx.x * 4 + (threadIdx.x >> 6);
  int lane = threadIdx.x & 63;
  const float* src;
  if (wid < NPTS)           src = s + (size_t)wid * DIM;
  else if (wid < NPTS + BQ) src = x + (size_t)(wid - NPTS) * DIM;
  else return;
  float4 v = reinterpret_cast<const float4*>(src)[lane];
  float ss = v.x * v.x + v.y * v.y + v.z * v.z + v.w * v.w;
  #pragma unroll
  for (int off = 32; off > 0; off >>= 1) ss += __shfl_xor(ss, off);
  if (lane == 0) {
    if (wid < NPTS) {
      ws[V1_S2 + wid] = ss;
      float lam = lambdas[wid];
      ws[V1_W + wid] = labels[wid] * (lam > 0.0f ? lam : 0.0f);
    } else {
      ws[V1_X2 + (wid - NPTS)] = ss;
    }
  }
}

__global__ __launch_bounds__(256) void svm_main(
    const float* __restrict__ x, const float* __restrict__ s,
    const float* __restrict__ ws) {
  __shared__ __bf16 sA[128 * BK];
  __shared__ __bf16 sB2[128 * BK];

  const int t    = threadIdx.x;
  const int wave = t >> 6;
  const int lane = t & 63;
  const int quad = lane >> 4;
  const int l16  = lane & 15;
  const int wm   = (wave & 1) * 64;
  const int wn   = (wave >> 1) * 64;
  const int bRow0 = blockIdx.y * 128;
  const int n0    = blockIdx.x * 128;

  f32x4 acc[4][4];
  #pragma unroll
  for (int i = 0; i < 4; ++i)
    #pragma unroll
    for (int j = 0; j < 4; ++j)
      acc[i][j] = (f32x4)(0.0f);

  for (int kt = 0; kt < DIM / BK; ++kt) {
    const int k0 = kt * BK;
    __syncthreads();
    #pragma unroll
    for (int i = 0; i < 4; ++i) {
      int slot = t + i * 256;
      int r  = slot >> 3;
      int c4 = slot & 7;
      float4 va = reinterpret_cast<const float4*>(
          x + (size_t)(bRow0 + r) * DIM + k0)[c4];
      bf16x4 ha = { (__bf16)va.x, (__bf16)va.y, (__bf16)va.z, (__bf16)va.w };
      *reinterpret_cast<bf16x4*>(&sA[r * BK + c4 * 4]) = ha;

      int nrow = n0 + r;
      float4 vb = make_float4(0.f, 0.f, 0.f, 0.f);
      if (nrow < NPTS)
        vb = reinterpret_cast<const float4*>(
            s + (size_t)nrow * DIM + k0)[c4];
      bf16x4 hb = { (__bf16)vb.x, (__bf16)vb.y, (__bf16)vb.z, (__bf16)vb.w };
      *reinterpret_cast<bf16x4*>(&sB2[r * BK + c4 * 4]) = hb;
    }
    __syncthreads();

    bf16x8 af[4], bfv[4];
    #pragma unroll
    for (int mi = 0; mi < 4; ++mi)
      af[mi] = *reinterpret_cast<const bf16x8*>(
          &sA[(wm + mi * 16 + l16) * BK + quad * 8]);
    #pragma unroll
    for (int ni = 0; ni < 4; ++ni)
      bfv[ni] = *reinterpret_cast<const bf16x8*>(
          &sB2[(wn + ni * 16 + l16) * BK + quad * 8]);
    #pragma unroll
    for (int mi = 0; mi < 4; ++mi)
      #pragma unroll
      for (int ni = 0; ni < 4; ++ni)
        acc[mi][ni] = __builtin_amdgcn_mfma_f32_16x16x32_bf16(
            af[mi], bfv[ni], acc[mi][ni], 0, 0, 0);
  }

  const float* x2g = ws + V1_X2;
  const float* s2g = ws + V1_S2;
  const float* wg  = ws + V1_W;
  float* accOut    = (float*)ws + V1_ACC;

  float s2v[4], wv[4];
  #pragma unroll
  for (int ni = 0; ni < 4; ++ni) {
    int n = n0 + wn + ni * 16 + l16;
    bool ok = n < NPTS;
    s2v[ni] = ok ? s2g[n] : 0.0f;
    wv[ni]  = ok ? wg[n]  : 0.0f;
  }
  #pragma unroll
  for (int mi = 0; mi < 4; ++mi) {
    const int mbase = wm + mi * 16 + quad * 4;
    #pragma unroll
    for (int reg = 0; reg < 4; ++reg) {
      float x2r = x2g[bRow0 + mbase + reg];
      float ps = 0.0f;
      #pragma unroll
      for (int ni = 0; ni < 4; ++ni) {
        float cc = acc[mi][ni][reg];
        ps += __expf(__builtin_fmaf(-0.5f, x2r + s2v[ni], cc)) * wv[ni];
      }
      ps += __shfl_xor(ps, 1);
      ps += __shfl_xor(ps, 2);
      ps += __shfl_xor(ps, 4);
      ps += __shfl_xor(ps, 8);
      if (l16 == 0) atomicAdd(&accOut[bRow0 + mbase + reg], ps);
    }
  }
}

// ============================================================

__global__ __launch_bounds__(256) void svm_finalize(
    const float* __restrict__ ws, const float* __restrict__ bias,
    float* __restrict__ out) {
  int i = blockIdx.x * 256 + threadIdx.x;
  if (i < BQ) out[i] = tanhf(ws[i] + bias[0]);  // acc at offset 0 in all layouts
}

extern "C" void kernel_launch(void* const* d_in, const int* in_sizes, int n_in,
                              void* d_out, int out_size, void* d_ws, size_t ws_size,
                              hipStream_t stream) {
  const float* x       = (const float*)d_in[0];  // [2048, 256]
  const float* s       = (const float*)d_in[1];  // [50000, 256]
  const float* labels  = (const float*)d_in[2];  // [50000]
  const float* lambdas = (const float*)d_in[3];  // [50000]
  const float* bias    = (const float*)d_in[4];  // [1]
  float* out = (float*)d_out;                    // [2048]
  float* ws  = (float*)d_ws;

  if (ws_size >= WS_TOTAL_BYTES) {
    // precvt9 zeroes the accumulator region itself (blocks 0..7)
    svm_precvt9<<<(NPAD + BQ + 3) / 4, 256, 0, stream>>>(x, s, labels, lambdas, ws);
    svm_main18<<<8 * NG, 256, 0, stream>>>(ws);
  } else {
    hipMemsetAsync(ws, 0, BQ * sizeof(float), stream);
    svm_precompute<<<(NPTS + BQ + 3) / 4, 256, 0, stream>>>(x, s, labels, lambdas, ws);
    dim3 grid(391, BQ / 128);
    svm_main<<<grid, 256, 0, stream>>>(x, s, ws);
  }
  svm_finalize<<<BQ / 256, 256, 0, stream>>>(ws, bias, out);
}